// Round 1
// baseline (37.442 us; speedup 1.0000x reference)
//
#include <hip/hip_runtime.h>

#define MARGIN 1.0f
#define BATCH 256
#define N 512
#define THREADS 256

// Kernel 1: one block per batch row. Computes
//   psum[b] = sum_{i rel, j nonrel} relu(MARGIN - (s_i - s_j))
//   pcnt[b] = num_rel * num_nonrel   (exact in fp32, <= 2^16)
__global__ __launch_bounds__(THREADS) void hinge_rows(
    const float* __restrict__ scores,
    const int* __restrict__ rel,
    float* __restrict__ psum,
    float* __restrict__ pcnt)
{
    __shared__ float s[N];
    __shared__ unsigned char r[N];
    __shared__ float wa[THREADS / 64];
    __shared__ float wc[THREADS / 64];

    const int b = blockIdx.x;
    const int tid = threadIdx.x;
    const float* srow = scores + b * N;
    const int* rrow = rel + b * N;

    // Stage row into LDS (coalesced: 256 lanes x 2 passes).
    for (int i = tid; i < N; i += THREADS) {
        s[i] = srow[i];
        r[i] = (unsigned char)(rrow[i] > 0 ? 1 : 0);
    }
    __syncthreads();

    float acc = 0.0f;
    int nrel = 0;
    // Each thread owns items tid and tid+256 as the "relevant" index i.
    for (int ii = 0; ii < N; ii += THREADS) {
        const int i = ii + tid;
        const int isrel = (int)r[i];
        nrel += isrel;
        if (isrel) {
            const float m = MARGIN - s[i];
            // j loop is wave-uniform -> s[j], r[j] broadcast from LDS.
            for (int j = 0; j < N; ++j) {
                float v = m + s[j];
                v = v > 0.0f ? v : 0.0f;
                acc += r[j] ? 0.0f : v;
            }
        }
    }

    // Wave (64-lane) tree reduction, then cross-wave via LDS.
    float a = acc;
    float c = (float)nrel;
    for (int off = 32; off > 0; off >>= 1) {
        a += __shfl_down(a, off, 64);
        c += __shfl_down(c, off, 64);
    }
    const int wave = tid >> 6;
    const int lane = tid & 63;
    if (lane == 0) { wa[wave] = a; wc[wave] = c; }
    __syncthreads();
    if (tid == 0) {
        const float ta = wa[0] + wa[1] + wa[2] + wa[3];
        const float nr = wc[0] + wc[1] + wc[2] + wc[3];
        psum[b] = ta;
        pcnt[b] = nr * ((float)N - nr);  // num_rel * num_nonrel, exact
    }
}

// Kernel 2: single block reduces the 256 per-row partials and divides.
__global__ __launch_bounds__(THREADS) void hinge_finalize(
    const float* __restrict__ psum,
    const float* __restrict__ pcnt,
    float* __restrict__ out)
{
    __shared__ float wa[THREADS / 64];
    __shared__ float wc[THREADS / 64];
    const int tid = threadIdx.x;

    float a = psum[tid];
    float c = pcnt[tid];
    for (int off = 32; off > 0; off >>= 1) {
        a += __shfl_down(a, off, 64);
        c += __shfl_down(c, off, 64);
    }
    const int wave = tid >> 6;
    const int lane = tid & 63;
    if (lane == 0) { wa[wave] = a; wc[wave] = c; }
    __syncthreads();
    if (tid == 0) {
        const float total = wa[0] + wa[1] + wa[2] + wa[3];
        const float cnt = wc[0] + wc[1] + wc[2] + wc[3];
        out[0] = cnt > 0.0f ? total / cnt : 0.0f;
    }
}

extern "C" void kernel_launch(void* const* d_in, const int* in_sizes, int n_in,
                              void* d_out, int out_size, void* d_ws, size_t ws_size,
                              hipStream_t stream) {
    const float* scores = (const float*)d_in[0];
    const int* rel = (const int*)d_in[1];
    float* out = (float*)d_out;

    // Workspace layout: 256 floats (per-row sums) + 256 floats (per-row counts).
    float* psum = (float*)d_ws;
    float* pcnt = psum + BATCH;

    hinge_rows<<<BATCH, THREADS, 0, stream>>>(scores, rel, psum, pcnt);
    hinge_finalize<<<1, THREADS, 0, stream>>>(psum, pcnt, out);
}

// Round 2
// 12.723 us; speedup vs baseline: 2.9428x; 2.9428x over previous
//
#include <hip/hip_runtime.h>

#define MARGIN 1.0f
#define BATCH 256
#define N 512
#define THREADS 256
#define JCHUNK 64
#define CHUNKS (N / JCHUNK)          // 8 j-chunks per row
#define NBLOCKS (BATCH * CHUNKS)     // 2048 blocks -> 8 blocks/CU, full occupancy

// Kernel 1: block (row, chunk) computes
//   psum[bid] = sum_{i in row, j in chunk} [i rel][j nonrel] relu(MARGIN - (s_i - s_j))
// using sentinel encoding so the inner loop is branch-free:
//   t[j]  = s_j   if j nonrel else -1e30   (m_i + t[j] << 0 -> relu = 0)
//   m_i   = 1-s_i if i rel    else -1e30
// Chunk-0 blocks additionally write pcnt[row] = num_rel * num_nonrel (exact fp32).
__global__ __launch_bounds__(THREADS) void hinge_pairs(
    const float* __restrict__ scores,
    const int* __restrict__ rel,
    float* __restrict__ psum,   // [NBLOCKS]
    float* __restrict__ pcnt)   // [BATCH]
{
    __shared__ float t[JCHUNK];
    __shared__ float wa[THREADS / 64];
    __shared__ float wc[THREADS / 64];

    const int bid = blockIdx.x;
    const int row = bid >> 3;                 // bid / CHUNKS
    const int chunk = bid & (CHUNKS - 1);
    const int tid = threadIdx.x;

    const float* srow = scores + row * N;
    const int* rrow = rel + row * N;

    // Stage this block's j-chunk with sentinels (threads 0..63, coalesced).
    if (tid < JCHUNK) {
        const int j = chunk * JCHUNK + tid;
        const float sj = srow[j];
        t[tid] = (rrow[j] == 0) ? sj : -1e30f;
    }

    // Each thread owns two candidate-i items (coalesced global loads).
    const float s0 = srow[tid];
    const float s1 = srow[tid + THREADS];
    const int r0 = rrow[tid] > 0;
    const int r1 = rrow[tid + THREADS] > 0;
    const float m0 = r0 ? (MARGIN - s0) : -1e30f;
    const float m1 = r1 ? (MARGIN - s1) : -1e30f;

    __syncthreads();

    float acc0 = 0.0f, acc1 = 0.0f;
    #pragma unroll 8
    for (int j = 0; j < JCHUNK; ++j) {
        const float tj = t[j];                 // uniform addr -> LDS broadcast
        const float v0 = m0 + tj;
        const float v1 = m1 + tj;
        acc0 += v0 > 0.0f ? v0 : 0.0f;
        acc1 += v1 > 0.0f ? v1 : 0.0f;
    }

    // Fixed-order block reduction (deterministic).
    float a = acc0 + acc1;
    float c = (float)(r0 + r1);
    for (int off = 32; off > 0; off >>= 1) {
        a += __shfl_down(a, off, 64);
        c += __shfl_down(c, off, 64);
    }
    const int wave = tid >> 6;
    const int lane = tid & 63;
    if (lane == 0) { wa[wave] = a; wc[wave] = c; }
    __syncthreads();
    if (tid == 0) {
        psum[bid] = wa[0] + wa[1] + wa[2] + wa[3];
        if (chunk == 0) {
            const float nr = wc[0] + wc[1] + wc[2] + wc[3];
            pcnt[row] = nr * ((float)N - nr);  // num_rel * num_nonrel, exact in fp32
        }
    }
}

// Kernel 2: single block reduces 2048 partial sums + 256 pair counts, divides.
__global__ __launch_bounds__(THREADS) void hinge_finalize(
    const float* __restrict__ psum,
    const float* __restrict__ pcnt,
    float* __restrict__ out)
{
    __shared__ float wa[THREADS / 64];
    __shared__ float wc[THREADS / 64];
    const int tid = threadIdx.x;

    float a = 0.0f;
    #pragma unroll
    for (int k = 0; k < NBLOCKS / THREADS; ++k)   // 8 coalesced passes
        a += psum[tid + k * THREADS];
    float c = pcnt[tid];

    for (int off = 32; off > 0; off >>= 1) {
        a += __shfl_down(a, off, 64);
        c += __shfl_down(c, off, 64);
    }
    const int wave = tid >> 6;
    const int lane = tid & 63;
    if (lane == 0) { wa[wave] = a; wc[wave] = c; }
    __syncthreads();
    if (tid == 0) {
        const float total = wa[0] + wa[1] + wa[2] + wa[3];
        const float cnt = wc[0] + wc[1] + wc[2] + wc[3];
        out[0] = cnt > 0.0f ? total / cnt : 0.0f;
    }
}

extern "C" void kernel_launch(void* const* d_in, const int* in_sizes, int n_in,
                              void* d_out, int out_size, void* d_ws, size_t ws_size,
                              hipStream_t stream) {
    const float* scores = (const float*)d_in[0];
    const int* rel = (const int*)d_in[1];
    float* out = (float*)d_out;

    // Workspace: 2048 floats (per-block sums) + 256 floats (per-row pair counts).
    float* psum = (float*)d_ws;
    float* pcnt = psum + NBLOCKS;

    hinge_pairs<<<NBLOCKS, THREADS, 0, stream>>>(scores, rel, psum, pcnt);
    hinge_finalize<<<1, THREADS, 0, stream>>>(psum, pcnt, out);
}